// Round 2
// baseline (746.405 us; speedup 1.0000x reference)
//
#include <hip/hip_runtime.h>

// CRF Viterbi decode: B=256, T=512, K=256, out (B, 514) as int32 tags.
// fwd pass stores masked state rows (max only, no argmax); bwd recomputes
// backpointers exactly via equality scan (f32 add/max are exact) with
// ballot+ffs, reproducing jnp.argmax first-occurrence tie-breaking.
// ws layout: states[B*T*K] f32 (128 MiB) + transT[K*K] f32 (256 KiB).

#define TK 256
#define TT 512

__global__ void transpose_kernel(const float* __restrict__ trans,
                                 float* __restrict__ transT) {
  int j = blockIdx.x;   // output row
  int i = threadIdx.x;  // output col
  transT[(size_t)j * TK + i] = trans[(size_t)i * TK + j];
}

// Forward: one block per batch, 512 threads = (j in [0,256)) x (h in {0,1}).
// Thread (j,h) holds trans[i][j] for i in [h*128, h*128+128) in registers and
// computes a partial max over its i-half; halves combined through LDS.
__global__ __launch_bounds__(512, 2) void crf_fwd(const float* __restrict__ em,
                                                  const float* __restrict__ trans,
                                                  const int* __restrict__ mask,
                                                  float* __restrict__ states) {
  const int b = blockIdx.x;
  const int tid = threadIdx.x;
  const int j = tid & (TK - 1);
  const int h = tid >> 8;  // wave-uniform: waves 0-3 -> h=0, waves 4-7 -> h=1

  __shared__ __align__(16) float st[TK];
  __shared__ float part[TK];
  __shared__ int mk[TT];

  // Stage trans column slice into registers (one-time, coalesced over j).
  float tr[128];
#pragma unroll
  for (int i = 0; i < 128; ++i)
    tr[i] = trans[(size_t)(h * 128 + i) * TK + j];

  mk[tid] = mask[(size_t)b * TT + tid];

  const size_t base = (size_t)b * TT * TK;
  if (h == 0) {
    float s0 = em[base + j];  // state0 = emissions[:,0,:]
    st[j] = s0;
    states[base + j] = s0;
  }
  __syncthreads();

  const float* stp = st + h * 128;
  for (int t = 1; t < TT; ++t) {
    float emv = 0.f;
    if (h == 0) emv = em[base + (size_t)t * TK + j];  // prefetch early

    float m0 = -INFINITY, m1 = -INFINITY;
#pragma unroll
    for (int k = 0; k < 32; ++k) {
      // uniform-address LDS broadcast of 4 state values
      const float4 s4 = *reinterpret_cast<const float4*>(stp + 4 * k);
      float a0 = s4.x + tr[4 * k + 0];
      float a1 = s4.y + tr[4 * k + 1];
      float a2 = s4.z + tr[4 * k + 2];
      float a3 = s4.w + tr[4 * k + 3];
      m0 = fmaxf(fmaxf(m0, a0), a1);  // hoping for v_max3_f32
      m1 = fmaxf(fmaxf(m1, a2), a3);
    }
    float m = fmaxf(m0, m1);
    if (h == 1) part[j] = m;
    __syncthreads();
    if (h == 0) {
      m = fmaxf(m, part[j]);
      float nv = (mk[t] > 0) ? (m + emv) : st[j];
      st[j] = nv;
      states[base + (size_t)t * TK + j] = nv;
    }
    __syncthreads();
  }
}

__device__ __forceinline__ float wave_max(float m) {
#pragma unroll
  for (int d = 1; d < 64; d <<= 1) m = fmaxf(m, __shfl_xor(m, d, 64));
  return m;
}

// First index i (lane-major: i = 4*lane + k) whose value equals m.
__device__ __forceinline__ int first_eq_idx(float s0, float s1, float s2,
                                            float s3, float m) {
  unsigned long long b0 = __ballot(s0 == m);
  unsigned long long b1 = __ballot(s1 == m);
  unsigned long long b2 = __ballot(s2 == m);
  unsigned long long b3 = __ballot(s3 == m);
  int best = 0x7fffffff;
  if (b0) best = min(best, 4 * (__ffsll(b0) - 1) + 0);
  if (b1) best = min(best, 4 * (__ffsll(b1) - 1) + 1);
  if (b2) best = min(best, 4 * (__ffsll(b2) - 1) + 2);
  if (b3) best = min(best, 4 * (__ffsll(b3) - 1) + 3);
  return best;
}

// Backward: one wave per batch; 511 serial steps of
//   prev = first i with state[t-1][i] + trans[i][tag] == max_i(...)
// (exactly reproduces the forward bp with jnp.argmax tie-breaking).
__global__ __launch_bounds__(64, 1) void crf_bwd(const float* __restrict__ states,
                                                 const float* __restrict__ transT,
                                                 const int* __restrict__ mask,
                                                 int* __restrict__ out,
                                                 int out_stride) {
  const int b = blockIdx.x;
  const int lane = threadIdx.x;

  __shared__ int mk[TT];
  for (int q = lane; q < TT; q += 64) mk[q] = mask[(size_t)b * TT + q];
  __syncthreads();

  const size_t sbase = (size_t)b * TT * TK;
  int* outp = out + (size_t)b * out_stride;

  // zero the pad region (harness poisons d_out once; we must write all of it)
  for (int q = TT + lane; q < out_stride; q += 64) outp[q] = 0;

  // last_tag = argmax_j states[b, T-1, :]
  const float* srow = states + sbase;
  float4 r = *reinterpret_cast<const float4*>(srow + (size_t)(TT - 1) * TK + 4 * lane);
  float lm = fmaxf(fmaxf(r.x, r.y), fmaxf(r.z, r.w));
  lm = wave_max(lm);
  int tag = first_eq_idx(r.x, r.y, r.z, r.w, lm);

  auto LOADROW = [&](int rr) -> float4 {
    return *reinterpret_cast<const float4*>(srow + (size_t)rr * TK + 4 * lane);
  };
  // step t uses state row t-1; 4-deep prefetch
  float4 p0 = LOADROW(TT - 2), p1 = LOADROW(TT - 3), p2 = LOADROW(TT - 4),
         p3 = LOADROW(TT - 5);

  auto STEP = [&](float4 pr, int t) {
    int mkt = mk[t];
    if (lane == 0) outp[t] = (mkt > 0) ? tag : 0;  // tags * mask
    const float4 tv =
        *reinterpret_cast<const float4*>(transT + (size_t)tag * TK + 4 * lane);
    float s0 = pr.x + tv.x;
    float s1 = pr.y + tv.y;
    float s2 = pr.z + tv.z;
    float s3 = pr.w + tv.w;
    float m = fmaxf(fmaxf(s0, s1), fmaxf(s2, s3));
    m = wave_max(m);
    int prev = first_eq_idx(s0, s1, s2, s3, m);
    tag = (mkt > 0) ? prev : tag;
  };

  int t = TT - 1;  // 511; 511 % 4 == 3 so loop exits at t == 3
  while (t >= 4) {
    STEP(p0, t);     if (t - 5 >= 0) p0 = LOADROW(t - 5);
    STEP(p1, t - 1); if (t - 6 >= 0) p1 = LOADROW(t - 6);
    STEP(p2, t - 2); if (t - 7 >= 0) p2 = LOADROW(t - 7);
    STEP(p3, t - 3); if (t - 8 >= 0) p3 = LOADROW(t - 8);
    t -= 4;
  }
  STEP(p0, 3);
  STEP(p1, 2);
  STEP(p2, 1);
  if (lane == 0) outp[0] = (mk[0] > 0) ? tag : 0;
}

extern "C" void kernel_launch(void* const* d_in, const int* in_sizes, int n_in,
                              void* d_out, int out_size, void* d_ws, size_t ws_size,
                              hipStream_t stream) {
  const float* em = (const float*)d_in[0];
  const float* trans = (const float*)d_in[1];
  const int* mask = (const int*)d_in[2];
  int* out = (int*)d_out;

  const int B = in_sizes[0] / (TT * TK);      // 256
  const int out_stride = out_size / B;        // 514

  // ws: states (B*T*K f32) then transT (K*K f32); needs ~128.3 MiB
  float* states = (float*)d_ws;
  float* transT = states + (size_t)B * TT * TK;

  transpose_kernel<<<TK, TK, 0, stream>>>(trans, transT);
  crf_fwd<<<B, 512, 0, stream>>>(em, trans, mask, states);
  crf_bwd<<<B, 64, 0, stream>>>(states, transT, mask, out, out_stride);
}

// Round 3
// 655.881 us; speedup vs baseline: 1.1380x; 1.1380x over previous
//
#include <hip/hip_runtime.h>

// CRF Viterbi decode: B=256, T=512, K=256, out (B, 514) as int32 tags.
// fwd: one block per batch, 1024 threads = (j:256) x (h:4). Thread (j,h)
// holds trans[i][j], i in [h*64,(h+1)*64) as 32x v2f in VGPRs (64 regs,
// under the 128-reg cap at 4 waves/SIMD so it stays in arch VGPRs).
// Per step: 32 v_pk_add_f32 + 32 v_max3_f32, 4-way combine via LDS.
// bwd: recompute backpointers via exact f32 equality scan (unchanged).
// ws layout: states[B*T*K] f32 (128 MiB) + transT[K*K] f32 (256 KiB).

#define TK 256
#define TT 512

typedef float v2f __attribute__((ext_vector_type(2)));

__global__ void transpose_kernel(const float* __restrict__ trans,
                                 float* __restrict__ transT) {
  int j = blockIdx.x;
  int i = threadIdx.x;
  transT[(size_t)j * TK + i] = trans[(size_t)i * TK + j];
}

__global__ __launch_bounds__(1024, 4) void crf_fwd(const float* __restrict__ em,
                                                   const float* __restrict__ trans,
                                                   const int* __restrict__ mask,
                                                   float* __restrict__ states) {
  const int b = blockIdx.x;
  const int tid = threadIdx.x;
  const int j = tid & (TK - 1);
  const int h = tid >> 8;  // 0..3, wave-uniform

  __shared__ __align__(16) float st[TK];
  __shared__ float part[3 * TK];
  __shared__ int mk[TT];

  // 64-element trans column slice (i in [h*64, h*64+64)) as 32 packed pairs.
  v2f tr2[32];
#pragma unroll
  for (int i = 0; i < 32; ++i) {
    tr2[i].x = trans[(size_t)(h * 64 + 2 * i + 0) * TK + j];
    tr2[i].y = trans[(size_t)(h * 64 + 2 * i + 1) * TK + j];
  }

  if (tid < TT) mk[tid] = mask[(size_t)b * TT + tid];

  const size_t base = (size_t)b * TT * TK;
  float cur = 0.f;
  if (h == 0) {
    cur = em[base + j];  // state0 = emissions[:,0,:]
    st[j] = cur;
    states[base + j] = cur;
  }
  __syncthreads();

  const float* stp = st + h * 64;
  const float* emp = em + base + TK + j;      // row t=1 (used by h==0 only)
  float* outp = states + base + TK + j;

  for (int t = 1; t < TT; ++t) {
    float emv = 0.f;
    if (h == 0) emv = *emp;  // issue early; consumed at iteration end

    float m0 = -INFINITY, m1 = -INFINITY;
#pragma unroll
    for (int k = 0; k < 16; ++k) {
      const float4 s4 = *reinterpret_cast<const float4*>(stp + 4 * k);  // bcast
      v2f a = {s4.x, s4.y};
      v2f c = {s4.z, s4.w};
      a = a + tr2[2 * k + 0];  // v_pk_add_f32
      c = c + tr2[2 * k + 1];
      m0 = fmaxf(fmaxf(m0, a.x), a.y);  // v_max3_f32
      m1 = fmaxf(fmaxf(m1, c.x), c.y);
    }
    const float pm = fmaxf(m0, m1);

    if (h) part[(h - 1) * TK + j] = pm;
    __syncthreads();
    if (h == 0) {
      float m = fmaxf(fmaxf(pm, part[j]),
                      fmaxf(part[TK + j], part[2 * TK + j]));
      float nv = (mk[t] > 0) ? (m + emv) : cur;
      cur = nv;
      st[j] = nv;
      *outp = nv;
      emp += TK;
      outp += TK;
    }
    __syncthreads();
  }
}

__device__ __forceinline__ float wave_max(float m) {
#pragma unroll
  for (int d = 1; d < 64; d <<= 1) m = fmaxf(m, __shfl_xor(m, d, 64));
  return m;
}

// First index i (lane-major: i = 4*lane + k) whose value equals m.
__device__ __forceinline__ int first_eq_idx(float s0, float s1, float s2,
                                            float s3, float m) {
  unsigned long long b0 = __ballot(s0 == m);
  unsigned long long b1 = __ballot(s1 == m);
  unsigned long long b2 = __ballot(s2 == m);
  unsigned long long b3 = __ballot(s3 == m);
  int best = 0x7fffffff;
  if (b0) best = min(best, 4 * (__ffsll(b0) - 1) + 0);
  if (b1) best = min(best, 4 * (__ffsll(b1) - 1) + 1);
  if (b2) best = min(best, 4 * (__ffsll(b2) - 1) + 2);
  if (b3) best = min(best, 4 * (__ffsll(b3) - 1) + 3);
  return best;
}

// Backward: one wave per batch; 511 serial steps. Recomputes the forward
// argmax exactly (f32 add/max bit-exact; first-occurrence tie-break).
__global__ __launch_bounds__(64, 1) void crf_bwd(const float* __restrict__ states,
                                                 const float* __restrict__ transT,
                                                 const int* __restrict__ mask,
                                                 int* __restrict__ out,
                                                 int out_stride) {
  const int b = blockIdx.x;
  const int lane = threadIdx.x;

  __shared__ int mk[TT];
  for (int q = lane; q < TT; q += 64) mk[q] = mask[(size_t)b * TT + q];
  __syncthreads();

  const size_t sbase = (size_t)b * TT * TK;
  int* outp = out + (size_t)b * out_stride;

  // zero the pad region (harness poisons d_out once)
  for (int q = TT + lane; q < out_stride; q += 64) outp[q] = 0;

  const float* srow = states + sbase;
  float4 r = *reinterpret_cast<const float4*>(srow + (size_t)(TT - 1) * TK + 4 * lane);
  float lm = fmaxf(fmaxf(r.x, r.y), fmaxf(r.z, r.w));
  lm = wave_max(lm);
  int tag = first_eq_idx(r.x, r.y, r.z, r.w, lm);

  auto LOADROW = [&](int rr) -> float4 {
    return *reinterpret_cast<const float4*>(srow + (size_t)rr * TK + 4 * lane);
  };
  float4 p0 = LOADROW(TT - 2), p1 = LOADROW(TT - 3), p2 = LOADROW(TT - 4),
         p3 = LOADROW(TT - 5);

  auto STEP = [&](float4 pr, int t) {
    int mkt = mk[t];
    if (lane == 0) outp[t] = (mkt > 0) ? tag : 0;  // tags * mask
    const float4 tv =
        *reinterpret_cast<const float4*>(transT + (size_t)tag * TK + 4 * lane);
    float s0 = pr.x + tv.x;
    float s1 = pr.y + tv.y;
    float s2 = pr.z + tv.z;
    float s3 = pr.w + tv.w;
    float m = fmaxf(fmaxf(s0, s1), fmaxf(s2, s3));
    m = wave_max(m);
    int prev = first_eq_idx(s0, s1, s2, s3, m);
    tag = (mkt > 0) ? prev : tag;
  };

  int t = TT - 1;
  while (t >= 4) {
    STEP(p0, t);     if (t - 5 >= 0) p0 = LOADROW(t - 5);
    STEP(p1, t - 1); if (t - 6 >= 0) p1 = LOADROW(t - 6);
    STEP(p2, t - 2); if (t - 7 >= 0) p2 = LOADROW(t - 7);
    STEP(p3, t - 3); if (t - 8 >= 0) p3 = LOADROW(t - 8);
    t -= 4;
  }
  STEP(p0, 3);
  STEP(p1, 2);
  STEP(p2, 1);
  if (lane == 0) outp[0] = (mk[0] > 0) ? tag : 0;
}

extern "C" void kernel_launch(void* const* d_in, const int* in_sizes, int n_in,
                              void* d_out, int out_size, void* d_ws, size_t ws_size,
                              hipStream_t stream) {
  const float* em = (const float*)d_in[0];
  const float* trans = (const float*)d_in[1];
  const int* mask = (const int*)d_in[2];
  int* out = (int*)d_out;

  const int B = in_sizes[0] / (TT * TK);      // 256
  const int out_stride = out_size / B;        // 514

  float* states = (float*)d_ws;
  float* transT = states + (size_t)B * TT * TK;

  transpose_kernel<<<TK, TK, 0, stream>>>(trans, transT);
  crf_fwd<<<B, 1024, 0, stream>>>(em, trans, mask, states);
  crf_bwd<<<B, 64, 0, stream>>>(states, transT, mask, out, out_stride);
}